// Round 3
// baseline (388.781 us; speedup 1.0000x reference)
//
#include <hip/hip_runtime.h>
#include <math.h>

// x: [B=8, C=1, D=3, H=1536, W=1536] fp32
// out = (x - maxpool3x3x3(x) + 1e-5 > 0) ? x : 0 (pool broadcast over depth).
// Separable: m = depth-max, mp = 3x3 spatial max of m.
// Register-rolling rows, 2-stage SW pipeline, branchless body, no LDS.

#define Hh   1536
#define Ww   1536
#define EPSf 1e-5f
#define RPW  8                    // output rows per wave
#define BPR  (4 * RPW)            // rows per block (4 waves) = 32
#define NBANDS 6                  // 256-col bands (64 lanes x float4)
#define NSTRIP (Hh / BPR)         // 48
#define PER_XCD (NSTRIP * NBANDS) // 288 blocks per batch; one batch per XCD

typedef float f4 __attribute__((ext_vector_type(4)));

__global__ __launch_bounds__(256, 4) void nms3d_kernel(const float* __restrict__ x,
                                                       float* __restrict__ out) {
    const int tid  = threadIdx.x;
    const int lane = tid & 63;
    const int wv   = tid >> 6;

    // XCD-aware mapping: blockIdx round-robins over 8 XCDs; give each XCD one
    // batch and stagger its strip order so batches (27 MiB apart = channel-
    // aliased) don't march the same addresses in lockstep.
    const int xcd = blockIdx.x & 7;
    int j = blockIdx.x >> 3;                 // 0..287
    j = (j + xcd * 37) % PER_XCD;
    const int band = j % NBANDS;
    const int s    = j / NBANDS;
    const int b    = xcd;

    const int w0 = band * 256;
    const int h0 = s * BPR + wv * RPW;

    const size_t plane = (size_t)Hh * Ww;
    const float* xb = x + (size_t)b * 3 * plane;
    float*       ob = out + (size_t)b * 3 * plane;
    const int wc = w0 + lane * 4;

    const float NI = -INFINITY;
    const float PI_ = INFINITY;

    // ---- one-time edge-column prefetch, lane-distributed ----
    // left edge col w0-1 rows h0-1..h0+RPW in lanes 0..RPW+1,
    // right edge col w0+256 same rows in lanes 32..32+RPW+1.
    float eV = NI;
    {
        const int r   = (lane < 32) ? lane : (lane - 32);
        const int ec  = (lane < 32) ? (w0 - 1) : (w0 + 256);
        const int h   = h0 - 1 + r;
        if (r < RPW + 2 && ec >= 0 && ec < Ww && h >= 0 && h < Hh) {
            const float* q = xb + (size_t)h * Ww + ec;
            eV = fmaxf(q[0], fmaxf(q[plane], q[2 * plane]));
        }
    }

    // ---- branchless row loader: clamped address + fmin(bound) fix ----
    auto loadm = [&](int h, f4& m, f4& a0, f4& a1, f4& a2) {
        int hc = h < 0 ? 0 : (h > Hh - 1 ? Hh - 1 : h);
        const float* p = xb + (size_t)hc * Ww + wc;
        a0 = *(const f4*)(p);
        a1 = *(const f4*)(p + plane);
        a2 = *(const f4*)(p + 2 * plane);
        const float bound = ((unsigned)h < (unsigned)Hh) ? PI_ : NI;
        m.x = fminf(fmaxf(a0.x, fmaxf(a1.x, a2.x)), bound);
        m.y = fminf(fmaxf(a0.y, fmaxf(a1.y, a2.y)), bound);
        m.z = fminf(fmaxf(a0.z, fmaxf(a1.z, a2.z)), bound);
        m.w = fminf(fmaxf(a0.w, fmaxf(a1.w, a2.w)), bound);
    };

    f4 m_p, m_c, m_n, m_f;
    f4 xc0, xc1, xc2, xn0, xn1, xn2, xf0, xf1, xf2;
    f4 t0, t1, t2;

    loadm(h0 - 1, m_p, t0, t1, t2);       // x of row h0-1 discarded
    loadm(h0,     m_c, xc0, xc1, xc2);
    loadm(h0 + 1, m_n, xn0, xn1, xn2);

#pragma unroll
    for (int i = 0; i < RPW; ++i) {
        if (i < RPW - 1)                   // compile-time under full unroll
            loadm(h0 + i + 2, m_f, xf0, xf1, xf2);

        // vertical max of depth-max rows i-1, i, i+1
        f4 vm;
        vm.x = fmaxf(m_p.x, fmaxf(m_c.x, m_n.x));
        vm.y = fmaxf(m_p.y, fmaxf(m_c.y, m_n.y));
        vm.z = fmaxf(m_p.z, fmaxf(m_c.z, m_n.z));
        vm.w = fmaxf(m_p.w, fmaxf(m_c.w, m_n.w));

        // horizontal halo: in-wave shuffle; band edges from prefetched lanes
        const float fl  = __shfl_up(vm.w, 1);
        const float fr  = __shfl_down(vm.x, 1);
        const float eLv = fmaxf(fmaxf(__shfl(eV, i), __shfl(eV, i + 1)),
                                __shfl(eV, i + 2));
        const float eRv = fmaxf(fmaxf(__shfl(eV, 32 + i), __shfl(eV, 33 + i)),
                                __shfl(eV, 34 + i));
        const float left  = (lane == 0)  ? eLv : fl;
        const float right = (lane == 63) ? eRv : fr;

        f4 mp;
        mp.x = fmaxf(left, fmaxf(vm.x, vm.y));
        mp.y = fmaxf(vm.x, fmaxf(vm.y, vm.z));
        mp.z = fmaxf(vm.y, fmaxf(vm.z, vm.w));
        mp.w = fmaxf(vm.z, fmaxf(vm.w, right));

        float* po = ob + (size_t)(h0 + i) * Ww + wc;
        f4 o;
        o.x = ((xc0.x - mp.x) + EPSf > 0.0f) ? xc0.x : 0.0f;
        o.y = ((xc0.y - mp.y) + EPSf > 0.0f) ? xc0.y : 0.0f;
        o.z = ((xc0.z - mp.z) + EPSf > 0.0f) ? xc0.z : 0.0f;
        o.w = ((xc0.w - mp.w) + EPSf > 0.0f) ? xc0.w : 0.0f;
        __builtin_nontemporal_store(o, (f4*)po);
        o.x = ((xc1.x - mp.x) + EPSf > 0.0f) ? xc1.x : 0.0f;
        o.y = ((xc1.y - mp.y) + EPSf > 0.0f) ? xc1.y : 0.0f;
        o.z = ((xc1.z - mp.z) + EPSf > 0.0f) ? xc1.z : 0.0f;
        o.w = ((xc1.w - mp.w) + EPSf > 0.0f) ? xc1.w : 0.0f;
        __builtin_nontemporal_store(o, (f4*)(po + plane));
        o.x = ((xc2.x - mp.x) + EPSf > 0.0f) ? xc2.x : 0.0f;
        o.y = ((xc2.y - mp.y) + EPSf > 0.0f) ? xc2.y : 0.0f;
        o.z = ((xc2.z - mp.z) + EPSf > 0.0f) ? xc2.z : 0.0f;
        o.w = ((xc2.w - mp.w) + EPSf > 0.0f) ? xc2.w : 0.0f;
        __builtin_nontemporal_store(o, (f4*)(po + 2 * plane));

        // rotate pipeline registers (renamed away by full unroll)
        m_p = m_c; m_c = m_n; m_n = m_f;
        xc0 = xn0; xc1 = xn1; xc2 = xn2;
        xn0 = xf0; xn1 = xf1; xn2 = xf2;
    }
}

extern "C" void kernel_launch(void* const* d_in, const int* in_sizes, int n_in,
                              void* d_out, int out_size, void* d_ws, size_t ws_size,
                              hipStream_t stream) {
    const float* x = (const float*)d_in[0];
    float* out = (float*)d_out;
    const int grid = 8 * NSTRIP * NBANDS;   // 2304 blocks
    nms3d_kernel<<<dim3(grid), dim3(256), 0, stream>>>(x, out);
}